// Round 2
// baseline (729.037 us; speedup 1.0000x reference)
//
#include <hip/hip_runtime.h>

// ---- problem constants ----
#define HWSZ 9216            // 96*96
#define CIN  256
#define NPER 8847360         // P*B*h*HW  (one output tensor, elements)
#define PSTRIDE 1474560      // B*h*HW (part stride)
#define IMG_STRIDE 2359296   // CIN*HW (p_fea batch stride)
#define BHW 92160            // h*HW (batch stride inside a part)

// ---- f32 weight workspace layout (element offsets) ----
#define OFF_WATT  18432
#define OFF_BATT  18492
#define OFF_WDPX  18498
#define OFF_BDP   18598
#define OFF_BPROJ 18608
#define OFF_WGATE 18668
#define OFF_BGATE 18788
#define OFF_WUPD  18794
#define OFF_BUPD  20594
#define WS_TOTAL  20654
// bf16 MFMA A-operand pack: ushort element offset (byte 82944, past f32 region)
#define A_OFF_U16 41472
#define A_ELEMS   20480      // 5 mtiles * 8 ksteps * 64 lanes * 8

typedef __attribute__((ext_vector_type(8))) short short8;
typedef __attribute__((ext_vector_type(4))) float f32x4;
typedef __attribute__((ext_vector_type(2))) float f32x2;

// ---- LDS layout (float element offsets). Total 6776 f32 = 27104 B ->
// 6 blocks/CU (6*27136 = 162816 <= 163840).
#define SS     66
#define L_S    0        // [70][66]  MFMA result (rows 0..9 dp-base, 10..69 proj)
#define L_DP1  4620     // [10][66]  dp of part 1
#define L_S1   5280     // [10][66]  sum_{q!=1} att_q * dp_q   (atomic)
#define L_SA   5940     // [66]      sum_{q!=1} att_q          (atomic)
#define L_ATT  6008     // [6][64]
#define L_GATE 6392     // [6][64]
#define L_TOT  6776

static __device__ __forceinline__ unsigned short f2b(float f) {
  union { float f; unsigned int i; } v; v.f = f;
  unsigned int u = v.i;
  return (unsigned short)((u + 0x7fffu + ((u >> 16) & 1u)) >> 16);  // RNE
}
static __device__ __forceinline__ float sigmoidf_(float x) {
  return 1.0f / (1.0f + __expf(-x));
}

// Gather f32 weights into d_ws AND pack the big [70x256] matrix (w_dp_f rows 0..9,
// w_proj rows 10..69) as bf16 MFMA A-fragments:
// A_pack[mtile][kstep][lane][j] = W[m=mtile*16+(lane&15)][k=kstep*32+((lane>>4)&3)*8+j]
__global__ void prep_weights(const float* __restrict__ w_att,
                             const float* __restrict__ b_att,
                             const float* __restrict__ w_dp_f,
                             const float* __restrict__ w_dp_x,
                             const float* __restrict__ b_dp,
                             const float* __restrict__ w_proj,
                             const float* __restrict__ b_proj,
                             const float* __restrict__ w_gate,
                             const float* __restrict__ b_gate,
                             const float* __restrict__ w_upd,
                             const float* __restrict__ b_upd,
                             float* __restrict__ ws)
{
  int i = blockIdx.x * 256 + threadIdx.x;
  if (i < A_ELEMS) {
    int j     = i & 7;
    int lane  = (i >> 3) & 63;
    int kstep = (i >> 9) & 7;
    int mtile = i >> 12;
    int m = mtile * 16 + (lane & 15);
    int k = kstep * 32 + ((lane >> 4) & 3) * 8 + j;
    float wv = (m < 10) ? w_dp_f[m * CIN + k]
             : (m < 70) ? w_proj[(m - 10) * CIN + k] : 0.f;
    ((unsigned short*)ws)[A_OFF_U16 + i] = f2b(wv);
  }
  if (i >= WS_TOTAL || i < OFF_WATT) return;
  float v;
  if      (i < OFF_BATT)  v = w_att [i - OFF_WATT ];
  else if (i < OFF_WDPX)  v = b_att [i - OFF_BATT ];
  else if (i < OFF_BDP)   v = w_dp_x[i - OFF_WDPX ];
  else if (i < OFF_BPROJ) v = b_dp  [i - OFF_BDP  ];
  else if (i < OFF_WGATE) v = b_proj[i - OFF_BPROJ];
  else if (i < OFF_BGATE) v = w_gate[i - OFF_WGATE];
  else if (i < OFF_WUPD)  v = b_gate[i - OFF_BGATE];
  else if (i < OFF_BUPD)  v = w_upd [i - OFF_WUPD ];
  else                    v = b_upd [i - OFF_BUPD ];
  ws[i] = v;
}

// grid = 2304 (=147456 px / 64), block = 256 (4 waves).
// Phases: [zero s1/sA | 2-deep-pipelined gather+MFMA | S write |
//          sched_barrier | prefetch xp2 + att/gate -> LDS]
//         barrier -> e1 (dp -> dp1 / s1,sA atomics) -> barrier -> e2.
// Register discipline (round-1 spilled at min-waves=6): xh is streamed, not
// kept; acc never overlaps the xp2 prefetch (sched_barrier); gather is
// pipelined 2-deep (t[2][8]) instead of 64 clustered loads.
__global__ __launch_bounds__(256, 6) void part_graph_main(
    const float* __restrict__ p_fea,
    const float* __restrict__ xp,
    const float* __restrict__ xh,
    const float* __restrict__ ws,
    float* __restrict__ out)
{
  __shared__ __align__(16) float smem[L_TOT];

  const int tid = threadIdx.x;
  const int b   = blockIdx.x / 144;
  const int s0  = (blockIdx.x % 144) * 64;

  // ---- zero the atomic accumulators (s1 + sA contiguous: 726 floats) ----
  for (int i = tid; i < 726; i += 256) smem[L_S1 + i] = 0.f;

  // ---- direct global gather of B-fragments fused with MFMA, 2-deep pipe ----
  // D[70x16] = W[70x256] @ F[256x16] per wave.
  const int lane = tid & 63, wv = tid >> 6;
  const int l15  = lane & 15, quad = lane >> 4;
  const float* pf = p_fea + (size_t)b * IMG_STRIDE + s0 + wv * 16 + l15
                  + (size_t)quad * 8 * HWSZ;
  const short8* ap = (const short8*)((const unsigned short*)ws + A_OFF_U16);

  f32x4 acc[5];
#pragma unroll
  for (int mt = 0; mt < 5; ++mt) acc[mt] = (f32x4){0.f, 0.f, 0.f, 0.f};

  float t[2][8];
#pragma unroll
  for (int j = 0; j < 8; ++j) t[0][j] = pf[(size_t)j * HWSZ];
#pragma unroll
  for (int ks = 0; ks < 8; ++ks) {
    if (ks < 7) {
#pragma unroll
      for (int j = 0; j < 8; ++j)
        t[(ks + 1) & 1][j] = pf[(size_t)((ks + 1) * 32 + j) * HWSZ];
    }
    short8 bf;
#pragma unroll
    for (int j = 0; j < 8; ++j) bf[j] = (short)f2b(t[ks & 1][j]);
#pragma unroll
    for (int mt = 0; mt < 5; ++mt)
      acc[mt] = __builtin_amdgcn_mfma_f32_16x16x32_bf16(
          ap[(mt * 8 + ks) * 64 + lane], bf, acc[mt], 0, 0, 0);
  }

  // ---- transpose acc -> S[m][px] (C/D: col=lane&15 -> pixel, row=quad*4+r) ----
#pragma unroll
  for (int mt = 0; mt < 5; ++mt) {
#pragma unroll
    for (int r = 0; r < 4; ++r) {
      int m = mt * 16 + quad * 4 + r;
      if (m < 70) smem[L_S + m * SS + wv * 16 + l15] = acc[mt][r];
    }
  }

  // pin: don't hoist the epilogue prefetch over live acc[] (round-1 spill cause)
  __builtin_amdgcn_sched_barrier(0);

  // ---- prefetch xp2; fold att/gate fully (no LDS dependence); xh streamed ----
  const int ep = tid >> 5;            // part 0..5 (tid<192)
  const int px = (tid & 31) * 2;      // even pixel pair
  const size_t ebase = (size_t)b * BHW + s0 + px;

  f32x2 xp2[10];
  f32x2 att2, gate2;
  if (tid < 192) {
    const float* xpb = xp + (size_t)ep * PSTRIDE + ebase;
    const float* xhb = xh + (size_t)(ep >= 4 ? 1 : 0) * PSTRIDE + ebase;
    float ba = ws[OFF_BATT + ep], bg = ws[OFF_BGATE + ep];
    f32x2 asum = {ba, ba}, gsum = {bg, bg};
#pragma unroll
    for (int ch = 0; ch < 10; ++ch)
      xp2[ch] = *(const f32x2*)(xpb + (size_t)ch * HWSZ);
#pragma unroll
    for (int ch = 0; ch < 10; ++ch) {
      f32x2 hv = *(const f32x2*)(xhb + (size_t)ch * HWSZ);
      float wa  = ws[OFF_WATT  + ep * 10 + ch];
      float wgx = ws[OFF_WGATE + ep * 20 + 10 + ch];
      float wgh = ws[OFF_WGATE + ep * 20 + ch];
      asum.x = fmaf(wa,  xp2[ch].x, asum.x); asum.y = fmaf(wa,  xp2[ch].y, asum.y);
      gsum.x = fmaf(wgx, xp2[ch].x, gsum.x); gsum.y = fmaf(wgx, xp2[ch].y, gsum.y);
      gsum.x = fmaf(wgh, hv.x,      gsum.x); gsum.y = fmaf(wgh, hv.y,      gsum.y);
    }
    att2.x  = sigmoidf_(asum.x); att2.y  = sigmoidf_(asum.y);
    gate2.x = sigmoidf_(gsum.x); gate2.y = sigmoidf_(gsum.y);
    *(f32x2*)&smem[L_ATT  + ep * 64 + px] = att2;
    *(f32x2*)&smem[L_GATE + ep * 64 + px] = gate2;
  }
  __syncthreads();

  // ---- epilogue 1: dp (needs S); att/gate already done ----
  if (tid < 192) {
    if (ep == 1) {
#pragma unroll
      for (int ch = 0; ch < 10; ++ch) {
        f32x2 t2 = *(const f32x2*)&smem[L_S + ch * SS + px];
        float bd = ws[OFF_BDP + ch];
        t2.x += bd; t2.y += bd;
#pragma unroll
        for (int j = 0; j < 10; ++j) {
          float w = ws[OFF_WDPX + ch * 10 + j];
          t2.x = fmaf(w, xp2[j].x, t2.x); t2.y = fmaf(w, xp2[j].y, t2.y);
        }
        t2.x = fmaxf(t2.x, 0.f); t2.y = fmaxf(t2.y, 0.f);
        *(f32x2*)&smem[L_DP1 + ch * SS + px] = t2;
      }
    } else {
#pragma unroll
      for (int ch = 0; ch < 10; ++ch) {
        f32x2 t2 = *(const f32x2*)&smem[L_S + ch * SS + px];
        float bd = ws[OFF_BDP + ch];
        t2.x += bd; t2.y += bd;
#pragma unroll
        for (int j = 0; j < 10; ++j) {
          float w = ws[OFF_WDPX + ch * 10 + j];
          t2.x = fmaf(w, xp2[j].x, t2.x); t2.y = fmaf(w, xp2[j].y, t2.y);
        }
        t2.x = fmaxf(t2.x, 0.f); t2.y = fmaxf(t2.y, 0.f);
        atomicAdd(&smem[L_S1 + ch * SS + px],     att2.x * t2.x);
        atomicAdd(&smem[L_S1 + ch * SS + px + 1], att2.y * t2.y);
      }
      atomicAdd(&smem[L_SA + px],     att2.x);
      atomicAdd(&smem[L_SA + px + 1], att2.y);
    }
  }
  __syncthreads();

  // ---- epilogue 2: xpp, xhp, update, stores ----
  if (tid < 192) {
    f32x2 att1 = *(const f32x2*)&smem[L_ATT + 64 + px];
    f32x2 aa = {0.f, 0.f}, sa2 = {0.f, 0.f};
    if (ep == 1) {
      sa2 = *(const f32x2*)&smem[L_SA + px];
    } else {
      aa.x = att1.x * att2.x; aa.y = att1.y * att2.y;
    }

    float* o0 = out + (size_t)ep * PSTRIDE + ebase;
    const float* wu = ws + OFF_WUPD + ep * 300;   // [10 out][30 in]

    f32x2 u[10];
#pragma unroll
    for (int q = 0; q < 10; ++q) {
      float bu = ws[OFF_BUPD + ep * 10 + q];
      u[q].x = bu; u[q].y = bu;
    }

#pragma unroll
    for (int ch = 0; ch < 10; ++ch) {
      // xpp
      f32x2 xpp;
      if (ep == 1) {
        f32x2 s1v = *(const f32x2*)&smem[L_S1 + ch * SS + px];
        xpp.x = att1.x * fmaf(sa2.x, xp2[ch].x, s1v.x);
        xpp.y = att1.y * fmaf(sa2.y, xp2[ch].y, s1v.y);
      } else {
        f32x2 d1 = *(const f32x2*)&smem[L_DP1 + ch * SS + px];
        xpp.x = aa.x * (d1.x + xp2[ch].x);
        xpp.y = aa.y * (d1.y + xp2[ch].y);
      }
      // xhp
      f32x2 pr = *(const f32x2*)&smem[L_S + (10 + ep * 10 + ch) * SS + px];
      float bp = ws[OFF_BPROJ + ep * 10 + ch];
      f32x2 xhp;
      xhp.x = gate2.x * (pr.x + bp); xhp.y = gate2.y * (pr.y + bp);

      *(f32x2*)(o0 + (size_t)ch * HWSZ + NPER)             = xpp;
      *(f32x2*)(o0 + (size_t)ch * HWSZ + 2 * (size_t)NPER) = xhp;

      // stream this input column into all 10 update accumulators
#pragma unroll
      for (int q = 0; q < 10; ++q) {
        float w0 = wu[q * 30 + ch];
        float w1 = wu[q * 30 + 10 + ch];
        float w2 = wu[q * 30 + 20 + ch];
        u[q].x = fmaf(w0, xp2[ch].x, u[q].x); u[q].y = fmaf(w0, xp2[ch].y, u[q].y);
        u[q].x = fmaf(w1, xpp.x,     u[q].x); u[q].y = fmaf(w1, xpp.y,     u[q].y);
        u[q].x = fmaf(w2, xhp.x,     u[q].x); u[q].y = fmaf(w2, xhp.y,     u[q].y);
      }
    }
#pragma unroll
    for (int q = 0; q < 10; ++q) {
      f32x2 r;
      r.x = xp2[q].x + fmaxf(u[q].x, 0.f);
      r.y = xp2[q].y + fmaxf(u[q].y, 0.f);
      *(f32x2*)(o0 + (size_t)q * HWSZ) = r;
    }
  }
}

extern "C" void kernel_launch(void* const* d_in, const int* in_sizes, int n_in,
                              void* d_out, int out_size, void* d_ws, size_t ws_size,
                              hipStream_t stream) {
  const float* p_fea = (const float*)d_in[0];
  const float* xp    = (const float*)d_in[1];
  const float* xh    = (const float*)d_in[2];
  float* ws = (float*)d_ws;

  prep_weights<<<(WS_TOTAL + 255) / 256, 256, 0, stream>>>(
      (const float*)d_in[3],  (const float*)d_in[4],
      (const float*)d_in[5],  (const float*)d_in[6],
      (const float*)d_in[7],  (const float*)d_in[8],
      (const float*)d_in[9],  (const float*)d_in[10],
      (const float*)d_in[11], (const float*)d_in[12],
      (const float*)d_in[13], ws);

  part_graph_main<<<2304, 256, 0, stream>>>(
      p_fea, xp, xh, ws, (float*)d_out);
}

// Round 3
// 688.820 us; speedup vs baseline: 1.0584x; 1.0584x over previous
//
#include <hip/hip_runtime.h>

// ---- problem constants ----
#define HWSZ 9216            // 96*96
#define CIN  256
#define NPER 8847360         // P*B*h*HW  (one output tensor, elements)
#define PSTRIDE 1474560      // B*h*HW (part stride)
#define IMG_STRIDE 2359296   // CIN*HW (p_fea batch stride)
#define BHW 92160            // h*HW (batch stride inside a part)

// ---- f32 weight workspace layout (element offsets) ----
#define OFF_WATT  18432
#define OFF_BATT  18492
#define OFF_WDPX  18498
#define OFF_BDP   18598
#define OFF_BPROJ 18608
#define OFF_WGATE 18668
#define OFF_BGATE 18788
#define OFF_WUPD  18794
#define OFF_BUPD  20594
#define WS_TOTAL  20654
// bf16 MFMA A-operand pack: ushort element offset (byte 82944, past f32 region)
#define A_OFF_U16 41472
#define A_ELEMS   20480      // 5 mtiles * 8 ksteps * 64 lanes * 8

typedef __attribute__((ext_vector_type(8))) short short8;
typedef __attribute__((ext_vector_type(4))) float f32x4;
typedef __attribute__((ext_vector_type(2))) float f32x2;

// ---- LDS layout (float element offsets). Total 6776 f32 = 27104 B.
#define SS     66
#define L_S    0        // [70][66]  MFMA result (rows 0..9 dp-base, 10..69 proj)
#define L_DP1  4620     // [10][66]  dp of part 1
#define L_S1   5280     // [10][66]  sum_{q!=1} att_q * dp_q   (atomic)
#define L_SA   5940     // [66]      sum_{q!=1} att_q          (atomic)
#define L_ATT  6008     // [6][64]
#define L_GATE 6392     // [6][64]
#define L_TOT  6776

static __device__ __forceinline__ unsigned short f2b(float f) {
  union { float f; unsigned int i; } v; v.f = f;
  unsigned int u = v.i;
  return (unsigned short)((u + 0x7fffu + ((u >> 16) & 1u)) >> 16);  // RNE
}
static __device__ __forceinline__ float sigmoidf_(float x) {
  return 1.0f / (1.0f + __expf(-x));
}

// Gather f32 weights into d_ws AND pack the big [70x256] matrix (w_dp_f rows 0..9,
// w_proj rows 10..69) as bf16 MFMA A-fragments:
// A_pack[mtile][kstep][lane][j] = W[m=mtile*16+(lane&15)][k=kstep*32+((lane>>4)&3)*8+j]
__global__ void prep_weights(const float* __restrict__ w_att,
                             const float* __restrict__ b_att,
                             const float* __restrict__ w_dp_f,
                             const float* __restrict__ w_dp_x,
                             const float* __restrict__ b_dp,
                             const float* __restrict__ w_proj,
                             const float* __restrict__ b_proj,
                             const float* __restrict__ w_gate,
                             const float* __restrict__ b_gate,
                             const float* __restrict__ w_upd,
                             const float* __restrict__ b_upd,
                             float* __restrict__ ws)
{
  int i = blockIdx.x * 256 + threadIdx.x;
  if (i < A_ELEMS) {
    int j     = i & 7;
    int lane  = (i >> 3) & 63;
    int kstep = (i >> 9) & 7;
    int mtile = i >> 12;
    int m = mtile * 16 + (lane & 15);
    int k = kstep * 32 + ((lane >> 4) & 3) * 8 + j;
    float wv = (m < 10) ? w_dp_f[m * CIN + k]
             : (m < 70) ? w_proj[(m - 10) * CIN + k] : 0.f;
    ((unsigned short*)ws)[A_OFF_U16 + i] = f2b(wv);
  }
  if (i >= WS_TOTAL || i < OFF_WATT) return;
  float v;
  if      (i < OFF_BATT)  v = w_att [i - OFF_WATT ];
  else if (i < OFF_WDPX)  v = b_att [i - OFF_BATT ];
  else if (i < OFF_BDP)   v = w_dp_x[i - OFF_WDPX ];
  else if (i < OFF_BPROJ) v = b_dp  [i - OFF_BDP  ];
  else if (i < OFF_WGATE) v = b_proj[i - OFF_BPROJ];
  else if (i < OFF_BGATE) v = w_gate[i - OFF_WGATE];
  else if (i < OFF_WUPD)  v = b_gate[i - OFF_BGATE];
  else if (i < OFF_BUPD)  v = w_upd [i - OFF_WUPD ];
  else                    v = b_upd [i - OFF_BUPD ];
  ws[i] = v;
}

// grid = 2304 (=147456 px / 64), block = 256 (4 waves).
// Phases: [zero s1/sA | 2-deep-pipelined gather+MFMA | S write |
//          sched_barrier | prefetch xp2 + att/gate -> LDS]
//         barrier -> e1 (dp -> dp1 / s1,sA atomics) -> barrier -> e2.
// min-waves: 5 (budget 96 VGPR). min-waves=6 (budget 80) made the allocator
// demote xp2/u/t/acc to scratch: VGPR_Count 40, +500 MB scratch RW traffic
// (rounds 1-2). 5 blocks/CU is LDS-safe (6*27136 would fit but VGPRs don't).
__global__ __launch_bounds__(256, 5) void part_graph_main(
    const float* __restrict__ p_fea,
    const float* __restrict__ xp,
    const float* __restrict__ xh,
    const float* __restrict__ ws,
    float* __restrict__ out)
{
  __shared__ __align__(16) float smem[L_TOT];

  const int tid = threadIdx.x;
  const int b   = blockIdx.x / 144;
  const int s0  = (blockIdx.x % 144) * 64;

  // ---- zero the atomic accumulators (s1 + sA contiguous: 726 floats) ----
  for (int i = tid; i < 726; i += 256) smem[L_S1 + i] = 0.f;

  // ---- direct global gather of B-fragments fused with MFMA, 2-deep pipe ----
  // D[70x16] = W[70x256] @ F[256x16] per wave.
  const int lane = tid & 63, wv = tid >> 6;
  const int l15  = lane & 15, quad = lane >> 4;
  const float* pf = p_fea + (size_t)b * IMG_STRIDE + s0 + wv * 16 + l15
                  + (size_t)quad * 8 * HWSZ;
  const short8* ap = (const short8*)((const unsigned short*)ws + A_OFF_U16);

  f32x4 acc[5];
#pragma unroll
  for (int mt = 0; mt < 5; ++mt) acc[mt] = (f32x4){0.f, 0.f, 0.f, 0.f};

  float t[2][8];
#pragma unroll
  for (int j = 0; j < 8; ++j) t[0][j] = pf[(size_t)j * HWSZ];
#pragma unroll
  for (int ks = 0; ks < 8; ++ks) {
    if (ks < 7) {
#pragma unroll
      for (int j = 0; j < 8; ++j)
        t[(ks + 1) & 1][j] = pf[(size_t)((ks + 1) * 32 + j) * HWSZ];
    }
    short8 bf;
#pragma unroll
    for (int j = 0; j < 8; ++j) bf[j] = (short)f2b(t[ks & 1][j]);
#pragma unroll
    for (int mt = 0; mt < 5; ++mt)
      acc[mt] = __builtin_amdgcn_mfma_f32_16x16x32_bf16(
          ap[(mt * 8 + ks) * 64 + lane], bf, acc[mt], 0, 0, 0);
  }

  // ---- transpose acc -> S[m][px] (C/D: col=lane&15 -> pixel, row=quad*4+r) ----
#pragma unroll
  for (int mt = 0; mt < 5; ++mt) {
#pragma unroll
    for (int r = 0; r < 4; ++r) {
      int m = mt * 16 + quad * 4 + r;
      if (m < 70) smem[L_S + m * SS + wv * 16 + l15] = acc[mt][r];
    }
  }

  // pin: don't hoist the epilogue prefetch over live acc[]
  __builtin_amdgcn_sched_barrier(0);

  // ---- prefetch xp2; fold att/gate fully (no LDS dependence); xh streamed ----
  const int ep = tid >> 5;            // part 0..5 (tid<192)
  const int px = (tid & 31) * 2;      // even pixel pair
  const size_t ebase = (size_t)b * BHW + s0 + px;

  f32x2 xp2[10];
  f32x2 att2, gate2;
  if (tid < 192) {
    const float* xpb = xp + (size_t)ep * PSTRIDE + ebase;
    const float* xhb = xh + (size_t)(ep >= 4 ? 1 : 0) * PSTRIDE + ebase;
    float ba = ws[OFF_BATT + ep], bg = ws[OFF_BGATE + ep];
    f32x2 asum = {ba, ba}, gsum = {bg, bg};
#pragma unroll
    for (int ch = 0; ch < 10; ++ch)
      xp2[ch] = *(const f32x2*)(xpb + (size_t)ch * HWSZ);
#pragma unroll
    for (int ch = 0; ch < 10; ++ch) {
      f32x2 hv = *(const f32x2*)(xhb + (size_t)ch * HWSZ);
      float wa  = ws[OFF_WATT  + ep * 10 + ch];
      float wgx = ws[OFF_WGATE + ep * 20 + 10 + ch];
      float wgh = ws[OFF_WGATE + ep * 20 + ch];
      asum.x = fmaf(wa,  xp2[ch].x, asum.x); asum.y = fmaf(wa,  xp2[ch].y, asum.y);
      gsum.x = fmaf(wgx, xp2[ch].x, gsum.x); gsum.y = fmaf(wgx, xp2[ch].y, gsum.y);
      gsum.x = fmaf(wgh, hv.x,      gsum.x); gsum.y = fmaf(wgh, hv.y,      gsum.y);
    }
    att2.x  = sigmoidf_(asum.x); att2.y  = sigmoidf_(asum.y);
    gate2.x = sigmoidf_(gsum.x); gate2.y = sigmoidf_(gsum.y);
    *(f32x2*)&smem[L_ATT  + ep * 64 + px] = att2;
    *(f32x2*)&smem[L_GATE + ep * 64 + px] = gate2;
  }
  __syncthreads();

  // ---- epilogue 1: dp (needs S); att/gate already done ----
  if (tid < 192) {
    if (ep == 1) {
#pragma unroll
      for (int ch = 0; ch < 10; ++ch) {
        f32x2 t2 = *(const f32x2*)&smem[L_S + ch * SS + px];
        float bd = ws[OFF_BDP + ch];
        t2.x += bd; t2.y += bd;
#pragma unroll
        for (int j = 0; j < 10; ++j) {
          float w = ws[OFF_WDPX + ch * 10 + j];
          t2.x = fmaf(w, xp2[j].x, t2.x); t2.y = fmaf(w, xp2[j].y, t2.y);
        }
        t2.x = fmaxf(t2.x, 0.f); t2.y = fmaxf(t2.y, 0.f);
        *(f32x2*)&smem[L_DP1 + ch * SS + px] = t2;
      }
    } else {
#pragma unroll
      for (int ch = 0; ch < 10; ++ch) {
        f32x2 t2 = *(const f32x2*)&smem[L_S + ch * SS + px];
        float bd = ws[OFF_BDP + ch];
        t2.x += bd; t2.y += bd;
#pragma unroll
        for (int j = 0; j < 10; ++j) {
          float w = ws[OFF_WDPX + ch * 10 + j];
          t2.x = fmaf(w, xp2[j].x, t2.x); t2.y = fmaf(w, xp2[j].y, t2.y);
        }
        t2.x = fmaxf(t2.x, 0.f); t2.y = fmaxf(t2.y, 0.f);
        atomicAdd(&smem[L_S1 + ch * SS + px],     att2.x * t2.x);
        atomicAdd(&smem[L_S1 + ch * SS + px + 1], att2.y * t2.y);
      }
      atomicAdd(&smem[L_SA + px],     att2.x);
      atomicAdd(&smem[L_SA + px + 1], att2.y);
    }
  }
  __syncthreads();

  // ---- epilogue 2: xpp, xhp, update, stores ----
  if (tid < 192) {
    f32x2 att1 = *(const f32x2*)&smem[L_ATT + 64 + px];
    f32x2 aa = {0.f, 0.f}, sa2 = {0.f, 0.f};
    if (ep == 1) {
      sa2 = *(const f32x2*)&smem[L_SA + px];
    } else {
      aa.x = att1.x * att2.x; aa.y = att1.y * att2.y;
    }

    float* o0 = out + (size_t)ep * PSTRIDE + ebase;
    const float* wu = ws + OFF_WUPD + ep * 300;   // [10 out][30 in]

    f32x2 u[10];
#pragma unroll
    for (int q = 0; q < 10; ++q) {
      float bu = ws[OFF_BUPD + ep * 10 + q];
      u[q].x = bu; u[q].y = bu;
    }

#pragma unroll
    for (int ch = 0; ch < 10; ++ch) {
      // xpp
      f32x2 xpp;
      if (ep == 1) {
        f32x2 s1v = *(const f32x2*)&smem[L_S1 + ch * SS + px];
        xpp.x = att1.x * fmaf(sa2.x, xp2[ch].x, s1v.x);
        xpp.y = att1.y * fmaf(sa2.y, xp2[ch].y, s1v.y);
      } else {
        f32x2 d1 = *(const f32x2*)&smem[L_DP1 + ch * SS + px];
        xpp.x = aa.x * (d1.x + xp2[ch].x);
        xpp.y = aa.y * (d1.y + xp2[ch].y);
      }
      // xhp
      f32x2 pr = *(const f32x2*)&smem[L_S + (10 + ep * 10 + ch) * SS + px];
      float bp = ws[OFF_BPROJ + ep * 10 + ch];
      f32x2 xhp;
      xhp.x = gate2.x * (pr.x + bp); xhp.y = gate2.y * (pr.y + bp);

      *(f32x2*)(o0 + (size_t)ch * HWSZ + NPER)             = xpp;
      *(f32x2*)(o0 + (size_t)ch * HWSZ + 2 * (size_t)NPER) = xhp;

      // stream this input column into all 10 update accumulators
#pragma unroll
      for (int q = 0; q < 10; ++q) {
        float w0 = wu[q * 30 + ch];
        float w1 = wu[q * 30 + 10 + ch];
        float w2 = wu[q * 30 + 20 + ch];
        u[q].x = fmaf(w0, xp2[ch].x, u[q].x); u[q].y = fmaf(w0, xp2[ch].y, u[q].y);
        u[q].x = fmaf(w1, xpp.x,     u[q].x); u[q].y = fmaf(w1, xpp.y,     u[q].y);
        u[q].x = fmaf(w2, xhp.x,     u[q].x); u[q].y = fmaf(w2, xhp.y,     u[q].y);
      }
    }
#pragma unroll
    for (int q = 0; q < 10; ++q) {
      f32x2 r;
      r.x = xp2[q].x + fmaxf(u[q].x, 0.f);
      r.y = xp2[q].y + fmaxf(u[q].y, 0.f);
      *(f32x2*)(o0 + (size_t)q * HWSZ) = r;
    }
  }
}

extern "C" void kernel_launch(void* const* d_in, const int* in_sizes, int n_in,
                              void* d_out, int out_size, void* d_ws, size_t ws_size,
                              hipStream_t stream) {
  const float* p_fea = (const float*)d_in[0];
  const float* xp    = (const float*)d_in[1];
  const float* xh    = (const float*)d_in[2];
  float* ws = (float*)d_ws;

  prep_weights<<<(WS_TOTAL + 255) / 256, 256, 0, stream>>>(
      (const float*)d_in[3],  (const float*)d_in[4],
      (const float*)d_in[5],  (const float*)d_in[6],
      (const float*)d_in[7],  (const float*)d_in[8],
      (const float*)d_in[9],  (const float*)d_in[10],
      (const float*)d_in[11], (const float*)d_in[12],
      (const float*)d_in[13], ws);

  part_graph_main<<<2304, 256, 0, stream>>>(
      p_fea, xp, xh, ws, (float*)d_out);
}

// Round 4
// 394.768 us; speedup vs baseline: 1.8467x; 1.7449x over previous
//
#include <hip/hip_runtime.h>

// ---- problem constants ----
#define HWSZ 9216            // 96*96
#define CIN  256
#define NPER 8847360         // P*B*h*HW  (one output tensor, elements)
#define PSTRIDE 1474560      // B*h*HW (part stride)
#define IMG_STRIDE 2359296   // CIN*HW (p_fea batch stride)
#define BHW 92160            // h*HW (batch stride inside a part)

// ---- f32 weight workspace layout (element offsets) ----
#define OFF_WATT  18432
#define OFF_BATT  18492
#define OFF_WDPX  18498
#define OFF_BDP   18598
#define OFF_BPROJ 18608
#define OFF_WGATE 18668
#define OFF_BGATE 18788
#define OFF_WUPD  18794
#define OFF_BUPD  20594
#define WS_TOTAL  20654
// bf16 MFMA A-operand pack: ushort element offset (byte 82944, past f32 region)
#define A_OFF_U16 41472
#define A_ELEMS   20480      // 5 mtiles * 8 ksteps * 64 lanes * 8

typedef __attribute__((ext_vector_type(8))) short short8;
typedef __attribute__((ext_vector_type(4))) float f32x4;
typedef __attribute__((ext_vector_type(2))) float f32x2;

// ---- LDS layout (float element offsets). Total 6776 f32 = 27104 B.
#define SS     66
#define L_S    0        // [70][66]  MFMA result (rows 0..9 dp-base, 10..69 proj)
#define L_DP1  4620     // [10][66]  dp of part 1
#define L_S1   5280     // [10][66]  sum_{q!=1} att_q * dp_q   (atomic)
#define L_SA   5940     // [66]      sum_{q!=1} att_q          (atomic)
#define L_ATT  6008     // [6][64]
#define L_GATE 6392     // [6][64]
#define L_TOT  6776

static __device__ __forceinline__ unsigned short f2b(float f) {
  union { float f; unsigned int i; } v; v.f = f;
  unsigned int u = v.i;
  return (unsigned short)((u + 0x7fffu + ((u >> 16) & 1u)) >> 16);  // RNE
}
static __device__ __forceinline__ float sigmoidf_(float x) {
  return 1.0f / (1.0f + __expf(-x));
}

// Gather f32 weights into d_ws AND pack the big [70x256] matrix (w_dp_f rows 0..9,
// w_proj rows 10..69) as bf16 MFMA A-fragments:
// A_pack[mtile][kstep][lane][j] = W[m=mtile*16+(lane&15)][k=kstep*32+((lane>>4)&3)*8+j]
__global__ void prep_weights(const float* __restrict__ w_att,
                             const float* __restrict__ b_att,
                             const float* __restrict__ w_dp_f,
                             const float* __restrict__ w_dp_x,
                             const float* __restrict__ b_dp,
                             const float* __restrict__ w_proj,
                             const float* __restrict__ b_proj,
                             const float* __restrict__ w_gate,
                             const float* __restrict__ b_gate,
                             const float* __restrict__ w_upd,
                             const float* __restrict__ b_upd,
                             float* __restrict__ ws)
{
  int i = blockIdx.x * 256 + threadIdx.x;
  if (i < A_ELEMS) {
    int j     = i & 7;
    int lane  = (i >> 3) & 63;
    int kstep = (i >> 9) & 7;
    int mtile = i >> 12;
    int m = mtile * 16 + (lane & 15);
    int k = kstep * 32 + ((lane >> 4) & 3) * 8 + j;
    float wv = (m < 10) ? w_dp_f[m * CIN + k]
             : (m < 70) ? w_proj[(m - 10) * CIN + k] : 0.f;
    ((unsigned short*)ws)[A_OFF_U16 + i] = f2b(wv);
  }
  if (i >= WS_TOTAL || i < OFF_WATT) return;
  float v;
  if      (i < OFF_BATT)  v = w_att [i - OFF_WATT ];
  else if (i < OFF_WDPX)  v = b_att [i - OFF_BATT ];
  else if (i < OFF_BDP)   v = w_dp_x[i - OFF_WDPX ];
  else if (i < OFF_BPROJ) v = b_dp  [i - OFF_BDP  ];
  else if (i < OFF_WGATE) v = b_proj[i - OFF_BPROJ];
  else if (i < OFF_BGATE) v = w_gate[i - OFF_WGATE];
  else if (i < OFF_WUPD)  v = b_gate[i - OFF_BGATE];
  else if (i < OFF_BUPD)  v = w_upd [i - OFF_WUPD ];
  else                    v = b_upd [i - OFF_BUPD ];
  ws[i] = v;
}

// grid = 2304 (=147456 px / 64), block = 256 (4 waves).
// Phases: [zero s1/sA | 2-deep-pipelined gather+MFMA | S write |
//          sched_barrier | prefetch xp2 + att/gate -> LDS]
//         barrier -> e1 (dp -> dp1 / s1,sA atomics) -> barrier -> e2.
// Launch bounds: NO min-waves clause. Evidence across rounds:
//   default (r0 structure): VGPR 76, WRITE = output size (no scratch)
//   min-waves=6: VGPR 40, +500 MB scratch RW   (allocator demotes arrays)
//   min-waves=5: VGPR 48, +440 MB scratch RW   (same, slightly less)
// The allocator must be left free; LDS (27136 B) still allows 6 blocks/CU,
// VGPR ~76 allows 6 waves/EU, so occupancy lands at 5-6 blocks/CU naturally.
__global__ __launch_bounds__(256) void part_graph_main(
    const float* __restrict__ p_fea,
    const float* __restrict__ xp,
    const float* __restrict__ xh,
    const float* __restrict__ ws,
    float* __restrict__ out)
{
  __shared__ __align__(16) float smem[L_TOT];

  const int tid = threadIdx.x;
  const int b   = blockIdx.x / 144;
  const int s0  = (blockIdx.x % 144) * 64;

  // ---- zero the atomic accumulators (s1 + sA contiguous: 726 floats) ----
  for (int i = tid; i < 726; i += 256) smem[L_S1 + i] = 0.f;

  // ---- direct global gather of B-fragments fused with MFMA, 2-deep pipe ----
  // D[70x16] = W[70x256] @ F[256x16] per wave.
  const int lane = tid & 63, wv = tid >> 6;
  const int l15  = lane & 15, quad = lane >> 4;
  const float* pf = p_fea + (size_t)b * IMG_STRIDE + s0 + wv * 16 + l15
                  + (size_t)quad * 8 * HWSZ;
  const short8* ap = (const short8*)((const unsigned short*)ws + A_OFF_U16);

  f32x4 acc[5];
#pragma unroll
  for (int mt = 0; mt < 5; ++mt) acc[mt] = (f32x4){0.f, 0.f, 0.f, 0.f};

  float t[2][8];
#pragma unroll
  for (int j = 0; j < 8; ++j) t[0][j] = pf[(size_t)j * HWSZ];
#pragma unroll
  for (int ks = 0; ks < 8; ++ks) {
    if (ks < 7) {
#pragma unroll
      for (int j = 0; j < 8; ++j)
        t[(ks + 1) & 1][j] = pf[(size_t)((ks + 1) * 32 + j) * HWSZ];
    }
    short8 bf;
#pragma unroll
    for (int j = 0; j < 8; ++j) bf[j] = (short)f2b(t[ks & 1][j]);
#pragma unroll
    for (int mt = 0; mt < 5; ++mt)
      acc[mt] = __builtin_amdgcn_mfma_f32_16x16x32_bf16(
          ap[(mt * 8 + ks) * 64 + lane], bf, acc[mt], 0, 0, 0);
  }

  // ---- transpose acc -> S[m][px] (C/D: col=lane&15 -> pixel, row=quad*4+r) ----
#pragma unroll
  for (int mt = 0; mt < 5; ++mt) {
#pragma unroll
    for (int r = 0; r < 4; ++r) {
      int m = mt * 16 + quad * 4 + r;
      if (m < 70) smem[L_S + m * SS + wv * 16 + l15] = acc[mt][r];
    }
  }

  // pin: don't hoist the epilogue prefetch over live acc[]
  __builtin_amdgcn_sched_barrier(0);

  // ---- prefetch xp2; fold att/gate fully (no LDS dependence); xh streamed ----
  const int ep = tid >> 5;            // part 0..5 (tid<192)
  const int px = (tid & 31) * 2;      // even pixel pair
  const size_t ebase = (size_t)b * BHW + s0 + px;

  f32x2 xp2[10];
  f32x2 att2, gate2;
  if (tid < 192) {
    const float* xpb = xp + (size_t)ep * PSTRIDE + ebase;
    const float* xhb = xh + (size_t)(ep >= 4 ? 1 : 0) * PSTRIDE + ebase;
    float ba = ws[OFF_BATT + ep], bg = ws[OFF_BGATE + ep];
    f32x2 asum = {ba, ba}, gsum = {bg, bg};
#pragma unroll
    for (int ch = 0; ch < 10; ++ch)
      xp2[ch] = *(const f32x2*)(xpb + (size_t)ch * HWSZ);
#pragma unroll
    for (int ch = 0; ch < 10; ++ch) {
      f32x2 hv = *(const f32x2*)(xhb + (size_t)ch * HWSZ);
      float wa  = ws[OFF_WATT  + ep * 10 + ch];
      float wgx = ws[OFF_WGATE + ep * 20 + 10 + ch];
      float wgh = ws[OFF_WGATE + ep * 20 + ch];
      asum.x = fmaf(wa,  xp2[ch].x, asum.x); asum.y = fmaf(wa,  xp2[ch].y, asum.y);
      gsum.x = fmaf(wgx, xp2[ch].x, gsum.x); gsum.y = fmaf(wgx, xp2[ch].y, gsum.y);
      gsum.x = fmaf(wgh, hv.x,      gsum.x); gsum.y = fmaf(wgh, hv.y,      gsum.y);
    }
    att2.x  = sigmoidf_(asum.x); att2.y  = sigmoidf_(asum.y);
    gate2.x = sigmoidf_(gsum.x); gate2.y = sigmoidf_(gsum.y);
    *(f32x2*)&smem[L_ATT  + ep * 64 + px] = att2;
    *(f32x2*)&smem[L_GATE + ep * 64 + px] = gate2;
  }
  __syncthreads();

  // ---- epilogue 1: dp (needs S); att/gate already done ----
  if (tid < 192) {
    if (ep == 1) {
#pragma unroll
      for (int ch = 0; ch < 10; ++ch) {
        f32x2 t2 = *(const f32x2*)&smem[L_S + ch * SS + px];
        float bd = ws[OFF_BDP + ch];
        t2.x += bd; t2.y += bd;
#pragma unroll
        for (int j = 0; j < 10; ++j) {
          float w = ws[OFF_WDPX + ch * 10 + j];
          t2.x = fmaf(w, xp2[j].x, t2.x); t2.y = fmaf(w, xp2[j].y, t2.y);
        }
        t2.x = fmaxf(t2.x, 0.f); t2.y = fmaxf(t2.y, 0.f);
        *(f32x2*)&smem[L_DP1 + ch * SS + px] = t2;
      }
    } else {
#pragma unroll
      for (int ch = 0; ch < 10; ++ch) {
        f32x2 t2 = *(const f32x2*)&smem[L_S + ch * SS + px];
        float bd = ws[OFF_BDP + ch];
        t2.x += bd; t2.y += bd;
#pragma unroll
        for (int j = 0; j < 10; ++j) {
          float w = ws[OFF_WDPX + ch * 10 + j];
          t2.x = fmaf(w, xp2[j].x, t2.x); t2.y = fmaf(w, xp2[j].y, t2.y);
        }
        t2.x = fmaxf(t2.x, 0.f); t2.y = fmaxf(t2.y, 0.f);
        atomicAdd(&smem[L_S1 + ch * SS + px],     att2.x * t2.x);
        atomicAdd(&smem[L_S1 + ch * SS + px + 1], att2.y * t2.y);
      }
      atomicAdd(&smem[L_SA + px],     att2.x);
      atomicAdd(&smem[L_SA + px + 1], att2.y);
    }
  }
  __syncthreads();

  // ---- epilogue 2: xpp, xhp, update, stores ----
  if (tid < 192) {
    f32x2 att1 = *(const f32x2*)&smem[L_ATT + 64 + px];
    f32x2 aa = {0.f, 0.f}, sa2 = {0.f, 0.f};
    if (ep == 1) {
      sa2 = *(const f32x2*)&smem[L_SA + px];
    } else {
      aa.x = att1.x * att2.x; aa.y = att1.y * att2.y;
    }

    float* o0 = out + (size_t)ep * PSTRIDE + ebase;
    const float* wu = ws + OFF_WUPD + ep * 300;   // [10 out][30 in]

    f32x2 u[10];
#pragma unroll
    for (int q = 0; q < 10; ++q) {
      float bu = ws[OFF_BUPD + ep * 10 + q];
      u[q].x = bu; u[q].y = bu;
    }

#pragma unroll
    for (int ch = 0; ch < 10; ++ch) {
      // xpp
      f32x2 xpp;
      if (ep == 1) {
        f32x2 s1v = *(const f32x2*)&smem[L_S1 + ch * SS + px];
        xpp.x = att1.x * fmaf(sa2.x, xp2[ch].x, s1v.x);
        xpp.y = att1.y * fmaf(sa2.y, xp2[ch].y, s1v.y);
      } else {
        f32x2 d1 = *(const f32x2*)&smem[L_DP1 + ch * SS + px];
        xpp.x = aa.x * (d1.x + xp2[ch].x);
        xpp.y = aa.y * (d1.y + xp2[ch].y);
      }
      // xhp
      f32x2 pr = *(const f32x2*)&smem[L_S + (10 + ep * 10 + ch) * SS + px];
      float bp = ws[OFF_BPROJ + ep * 10 + ch];
      f32x2 xhp;
      xhp.x = gate2.x * (pr.x + bp); xhp.y = gate2.y * (pr.y + bp);

      *(f32x2*)(o0 + (size_t)ch * HWSZ + NPER)             = xpp;
      *(f32x2*)(o0 + (size_t)ch * HWSZ + 2 * (size_t)NPER) = xhp;

      // stream this input column into all 10 update accumulators
#pragma unroll
      for (int q = 0; q < 10; ++q) {
        float w0 = wu[q * 30 + ch];
        float w1 = wu[q * 30 + 10 + ch];
        float w2 = wu[q * 30 + 20 + ch];
        u[q].x = fmaf(w0, xp2[ch].x, u[q].x); u[q].y = fmaf(w0, xp2[ch].y, u[q].y);
        u[q].x = fmaf(w1, xpp.x,     u[q].x); u[q].y = fmaf(w1, xpp.y,     u[q].y);
        u[q].x = fmaf(w2, xhp.x,     u[q].x); u[q].y = fmaf(w2, xhp.y,     u[q].y);
      }
    }
#pragma unroll
    for (int q = 0; q < 10; ++q) {
      f32x2 r;
      r.x = xp2[q].x + fmaxf(u[q].x, 0.f);
      r.y = xp2[q].y + fmaxf(u[q].y, 0.f);
      *(f32x2*)(o0 + (size_t)q * HWSZ) = r;
    }
  }
}

extern "C" void kernel_launch(void* const* d_in, const int* in_sizes, int n_in,
                              void* d_out, int out_size, void* d_ws, size_t ws_size,
                              hipStream_t stream) {
  const float* p_fea = (const float*)d_in[0];
  const float* xp    = (const float*)d_in[1];
  const float* xh    = (const float*)d_in[2];
  float* ws = (float*)d_ws;

  prep_weights<<<(WS_TOTAL + 255) / 256, 256, 0, stream>>>(
      (const float*)d_in[3],  (const float*)d_in[4],
      (const float*)d_in[5],  (const float*)d_in[6],
      (const float*)d_in[7],  (const float*)d_in[8],
      (const float*)d_in[9],  (const float*)d_in[10],
      (const float*)d_in[11], (const float*)d_in[12],
      (const float*)d_in[13], ws);

  part_graph_main<<<2304, 256, 0, stream>>>(
      p_fea, xp, xh, ws, (float*)d_out);
}

// Round 5
// 337.012 us; speedup vs baseline: 2.1632x; 1.1714x over previous
//
#include <hip/hip_runtime.h>

// ---- problem constants ----
#define HWSZ 9216            // 96*96
#define CIN  256
#define NPER 8847360         // P*B*h*HW  (one output tensor, elements)
#define PSTRIDE 1474560      // B*h*HW (part stride)
#define IMG_STRIDE 2359296   // CIN*HW (p_fea batch stride)
#define BHW 92160            // h*HW (batch stride inside a part)

// ---- f32 weight workspace layout (element offsets) ----
#define OFF_WATT  18432
#define OFF_BATT  18492
#define OFF_WDPX  18498
#define OFF_BDP   18598
#define OFF_BPROJ 18608
#define OFF_WGATE 18668
#define OFF_BGATE 18788
#define OFF_WUPD  18794
#define OFF_BUPD  20594
#define WS_TOTAL  20654
// bf16 MFMA A-operand pack: ushort element offset (byte 82944, past f32 region)
#define A_OFF_U16 41472
#define A_ELEMS   20480      // 5 mtiles * 8 ksteps * 64 lanes * 8

typedef __attribute__((ext_vector_type(8))) short short8;
typedef __attribute__((ext_vector_type(4))) float f32x4;

// ---- LDS layout (float element offsets). Total 6776 f32 = 27104 B.
#define SS     66
#define L_S    0        // [70][66]  MFMA result (rows 0..9 dp-base, 10..69 proj)
#define L_DP1  4620     // [10][66]  dp of part 1
#define L_S1   5280     // [10][66]  sum_{q!=1} att_q * dp_q   (atomic)
#define L_SA   5940     // [66]      sum_{q!=1} att_q          (atomic)
#define L_ATT  6008     // [6][64]
#define L_GATE 6392     // [6][64]
#define L_TOT  6776

static __device__ __forceinline__ unsigned short f2b(float f) {
  union { float f; unsigned int i; } v; v.f = f;
  unsigned int u = v.i;
  return (unsigned short)((u + 0x7fffu + ((u >> 16) & 1u)) >> 16);  // RNE
}
static __device__ __forceinline__ float sigmoidf_(float x) {
  return 1.0f / (1.0f + __expf(-x));
}

// Gather f32 weights into d_ws AND pack the big [70x256] matrix (w_dp_f rows 0..9,
// w_proj rows 10..69) as bf16 MFMA A-fragments:
// A_pack[mtile][kstep][lane][j] = W[m=mtile*16+(lane&15)][k=kstep*32+((lane>>4)&3)*8+j]
__global__ void prep_weights(const float* __restrict__ w_att,
                             const float* __restrict__ b_att,
                             const float* __restrict__ w_dp_f,
                             const float* __restrict__ w_dp_x,
                             const float* __restrict__ b_dp,
                             const float* __restrict__ w_proj,
                             const float* __restrict__ b_proj,
                             const float* __restrict__ w_gate,
                             const float* __restrict__ b_gate,
                             const float* __restrict__ w_upd,
                             const float* __restrict__ b_upd,
                             float* __restrict__ ws)
{
  int i = blockIdx.x * 256 + threadIdx.x;
  if (i < A_ELEMS) {
    int j     = i & 7;
    int lane  = (i >> 3) & 63;
    int kstep = (i >> 9) & 7;
    int mtile = i >> 12;
    int m = mtile * 16 + (lane & 15);
    int k = kstep * 32 + ((lane >> 4) & 3) * 8 + j;
    float wv = (m < 10) ? w_dp_f[m * CIN + k]
             : (m < 70) ? w_proj[(m - 10) * CIN + k] : 0.f;
    ((unsigned short*)ws)[A_OFF_U16 + i] = f2b(wv);
  }
  if (i >= WS_TOTAL || i < OFF_WATT) return;
  float v;
  if      (i < OFF_BATT)  v = w_att [i - OFF_WATT ];
  else if (i < OFF_WDPX)  v = b_att [i - OFF_BATT ];
  else if (i < OFF_BDP)   v = w_dp_x[i - OFF_WDPX ];
  else if (i < OFF_BPROJ) v = b_dp  [i - OFF_BDP  ];
  else if (i < OFF_WGATE) v = b_proj[i - OFF_BPROJ];
  else if (i < OFF_BGATE) v = w_gate[i - OFF_WGATE];
  else if (i < OFF_WUPD)  v = b_gate[i - OFF_BGATE];
  else if (i < OFF_BUPD)  v = w_upd [i - OFF_WUPD ];
  else                    v = b_upd [i - OFF_BUPD ];
  ws[i] = v;
}

// ---- epilogue helpers: part p is WAVE-UNIFORM (p = wave, or 4+wave in pass B).
// readfirstlane pins all weight/output bases to SGPRs. Round-4 lesson: a
// half-wave part index (tid>>5) made every weight access lane-divergent ->
// hundreds of VGPR-resident weight values -> VGPR 180 -> 2 blocks/CU.

// prefetch + att/gate (no LDS dependence; xh streamed, never kept)
static __device__ __forceinline__ void prefetch_ag(
    int p, int px, size_t ebase,
    const float* __restrict__ xp, const float* __restrict__ xh,
    const float* __restrict__ ws, float* __restrict__ smem,
    float* __restrict__ xpv, float& att)
{
  const int pu = __builtin_amdgcn_readfirstlane(p);
  const float* xpb = xp + (size_t)pu * PSTRIDE + ebase;
  const float* xhb = xh + (size_t)(pu >= 4 ? 1 : 0) * PSTRIDE + ebase;
  float asum = ws[OFF_BATT + pu], gsum = ws[OFF_BGATE + pu];
#pragma unroll
  for (int ch = 0; ch < 10; ++ch)
    xpv[ch] = xpb[(size_t)ch * HWSZ];
#pragma unroll
  for (int ch = 0; ch < 10; ++ch) {
    float hv = xhb[(size_t)ch * HWSZ];
    asum = fmaf(ws[OFF_WATT  + pu * 10 + ch],      xpv[ch], asum);
    gsum = fmaf(ws[OFF_WGATE + pu * 20 + 10 + ch], xpv[ch], gsum);
    gsum = fmaf(ws[OFF_WGATE + pu * 20 + ch],      hv,      gsum);
  }
  att = sigmoidf_(asum);
  smem[L_ATT  + pu * 64 + px] = att;
  smem[L_GATE + pu * 64 + px] = sigmoidf_(gsum);
}

// e1: dp from S + xpv; part 1 -> dpL; others -> s1/sA atomics
static __device__ __forceinline__ void e1_body(
    int p, int px, const float* __restrict__ ws,
    float* __restrict__ smem, const float* __restrict__ xpv, float att)
{
#pragma unroll
  for (int ch = 0; ch < 10; ++ch) {
    float tv = smem[L_S + ch * SS + px] + ws[OFF_BDP + ch];
#pragma unroll
    for (int j = 0; j < 10; ++j)
      tv = fmaf(ws[OFF_WDPX + ch * 10 + j], xpv[j], tv);
    tv = fmaxf(tv, 0.f);
    if (p == 1) smem[L_DP1 + ch * SS + px] = tv;
    else        atomicAdd(&smem[L_S1 + ch * SS + px], att * tv);
  }
  if (p != 1) atomicAdd(&smem[L_SA + px], att);
}

// e2: xpp, xhp, update, stores
static __device__ __forceinline__ void e2_body(
    int p, int px, size_t ebase, const float* __restrict__ ws,
    const float* __restrict__ smem, const float* __restrict__ xpv,
    float* __restrict__ out)
{
  const int pu = __builtin_amdgcn_readfirstlane(p);
  float attp = smem[L_ATT + pu * 64 + px];
  float att1 = smem[L_ATT + 64 + px];
  float g    = smem[L_GATE + pu * 64 + px];
  float aa   = att1 * attp;
  float sa   = smem[L_SA + px];

  float* o0 = out + (size_t)pu * PSTRIDE + ebase;
  const float* wu = ws + OFF_WUPD + pu * 300;   // [10 out][30 in], SGPR base

  float u[10];
#pragma unroll
  for (int q = 0; q < 10; ++q) u[q] = ws[OFF_BUPD + pu * 10 + q];

#pragma unroll
  for (int ch = 0; ch < 10; ++ch) {
    float xpp;
    if (pu == 1)
      xpp = att1 * fmaf(sa, xpv[ch], smem[L_S1 + ch * SS + px]);
    else
      xpp = aa * (smem[L_DP1 + ch * SS + px] + xpv[ch]);
    float pr  = smem[L_S + (10 + pu * 10 + ch) * SS + px];
    float xhp = g * (pr + ws[OFF_BPROJ + pu * 10 + ch]);

    o0[(size_t)ch * HWSZ + NPER]             = xpp;
    o0[(size_t)ch * HWSZ + 2 * (size_t)NPER] = xhp;

#pragma unroll
    for (int q = 0; q < 10; ++q) {
      u[q] = fmaf(wu[q * 30 + ch],      xpv[ch], u[q]);
      u[q] = fmaf(wu[q * 30 + 10 + ch], xpp,     u[q]);
      u[q] = fmaf(wu[q * 30 + 20 + ch], xhp,     u[q]);
    }
  }
#pragma unroll
  for (int q = 0; q < 10; ++q)
    o0[(size_t)q * HWSZ] = xpv[q] + fmaxf(u[q], 0.f);
}

// grid = 2304 (=147456 px / 64), block = 256 (4 waves).
// Phases: [zero s1/sA | 2-deep-pipelined gather+MFMA | S write | sched_barrier |
//          prefetch xpv + att/gate (pass A: parts 0-3 on waves 0-3;
//          pass B pre-issued: parts 4-5 on waves 0-1)]
//   barrier -> e1 A (+B on waves 0-1) -> barrier -> e2 A (+B).
// Launch bounds: NO min-waves clause (rounds 1-3: forcing a VGPR budget makes
// the allocator demote whole arrays to scratch -> +450 MB RW traffic).
__global__ __launch_bounds__(256) void part_graph_main(
    const float* __restrict__ p_fea,
    const float* __restrict__ xp,
    const float* __restrict__ xh,
    const float* __restrict__ ws,
    float* __restrict__ out)
{
  __shared__ __align__(16) float smem[L_TOT];

  const int tid = threadIdx.x;
  const int b   = blockIdx.x / 144;
  const int s0  = (blockIdx.x % 144) * 64;

  // ---- zero the atomic accumulators (s1 + sA contiguous: 726 floats) ----
  for (int i = tid; i < 726; i += 256) smem[L_S1 + i] = 0.f;

  // ---- direct global gather of B-fragments fused with MFMA, 2-deep pipe ----
  // D[70x16] = W[70x256] @ F[256x16] per wave.
  const int lane = tid & 63, wv = tid >> 6;
  const int l15  = lane & 15, quad = lane >> 4;
  const float* pf = p_fea + (size_t)b * IMG_STRIDE + s0 + wv * 16 + l15
                  + (size_t)quad * 8 * HWSZ;
  const short8* ap = (const short8*)((const unsigned short*)ws + A_OFF_U16);

  f32x4 acc[5];
#pragma unroll
  for (int mt = 0; mt < 5; ++mt) acc[mt] = (f32x4){0.f, 0.f, 0.f, 0.f};

  float t[2][8];
#pragma unroll
  for (int j = 0; j < 8; ++j) t[0][j] = pf[(size_t)j * HWSZ];
#pragma unroll
  for (int ks = 0; ks < 8; ++ks) {
    if (ks < 7) {
#pragma unroll
      for (int j = 0; j < 8; ++j)
        t[(ks + 1) & 1][j] = pf[(size_t)((ks + 1) * 32 + j) * HWSZ];
    }
    short8 bf;
#pragma unroll
    for (int j = 0; j < 8; ++j) bf[j] = (short)f2b(t[ks & 1][j]);
#pragma unroll
    for (int mt = 0; mt < 5; ++mt)
      acc[mt] = __builtin_amdgcn_mfma_f32_16x16x32_bf16(
          ap[(mt * 8 + ks) * 64 + lane], bf, acc[mt], 0, 0, 0);
  }

  // ---- transpose acc -> S[m][px] (C/D: col=lane&15 -> pixel, row=quad*4+r) ----
#pragma unroll
  for (int mt = 0; mt < 5; ++mt) {
#pragma unroll
    for (int r = 0; r < 4; ++r) {
      int m = mt * 16 + quad * 4 + r;
      if (m < 70) smem[L_S + m * SS + wv * 16 + l15] = acc[mt][r];
    }
  }

  // pin: don't hoist the epilogue prefetch over live acc[]
  __builtin_amdgcn_sched_barrier(0);

  // ---- prefetch: wave w -> part w (1 px/lane); waves 0-1 also pre-issue
  //      parts 4-5 so pass-B load latency hides under the barrier wait ----
  const int px = lane;
  const size_t ebase = (size_t)b * BHW + s0 + px;

  float xpv[10], att2;
  float xpvB[10], attB;
  prefetch_ag(wv, px, ebase, xp, xh, ws, smem, xpv, att2);
  if (wv < 2)
    prefetch_ag(4 + wv, px, ebase, xp, xh, ws, smem, xpvB, attB);
  __syncthreads();

  // ---- epilogue 1: dp -> dp1 / s1,sA atomics ----
  e1_body(wv, px, ws, smem, xpv, att2);
  if (wv < 2)
    e1_body(4 + wv, px, ws, smem, xpvB, attB);
  __syncthreads();

  // ---- epilogue 2: xpp, xhp, update, stores ----
  e2_body(wv, px, ebase, ws, smem, xpv, out);
  if (wv < 2)
    e2_body(4 + wv, px, ebase, ws, smem, xpvB, out);
}

extern "C" void kernel_launch(void* const* d_in, const int* in_sizes, int n_in,
                              void* d_out, int out_size, void* d_ws, size_t ws_size,
                              hipStream_t stream) {
  const float* p_fea = (const float*)d_in[0];
  const float* xp    = (const float*)d_in[1];
  const float* xh    = (const float*)d_in[2];
  float* ws = (float*)d_ws;

  prep_weights<<<(WS_TOTAL + 255) / 256, 256, 0, stream>>>(
      (const float*)d_in[3],  (const float*)d_in[4],
      (const float*)d_in[5],  (const float*)d_in[6],
      (const float*)d_in[7],  (const float*)d_in[8],
      (const float*)d_in[9],  (const float*)d_in[10],
      (const float*)d_in[11], (const float*)d_in[12],
      (const float*)d_in[13], ws);

  part_graph_main<<<2304, 256, 0, stream>>>(
      p_fea, xp, xh, ws, (float*)d_out);
}